// Round 3
// 977.871 us; speedup vs baseline: 1.0297x; 1.0297x over previous
//
#include <hip/hip_runtime.h>

// ---------------- problem constants (match setup_inputs) ----------------
#define E0 506880
#define E1 30720
#define E2 2560
#define NN0 540672
#define NN1 33792
#define NN2 3072
#define NN3 512
#define F_IN 256
#define F_HID 1024
#define F_OUT 47

typedef __attribute__((ext_vector_type(8))) short short8;  // 8 bf16 = 4 VGPRs
typedef __attribute__((ext_vector_type(4))) float f32x4;   // MFMA C/D frag

// address-space-typed pointers for global_load_lds
typedef __attribute__((address_space(1))) const unsigned int as1_u32;
typedef __attribute__((address_space(3))) unsigned int as3_u32;

// async global->LDS, 16B per lane; LDS dest = wave-uniform base + lane*16
__device__ __forceinline__ void gload16(const unsigned short* g, unsigned short* l) {
    __builtin_amdgcn_global_load_lds((as1_u32*)g, (as3_u32*)l, 16, 0, 0);
}

__device__ __forceinline__ float bf_lo(unsigned int u) {
    return __uint_as_float(u << 16);
}
__device__ __forceinline__ float bf_hi(unsigned int u) {
    return __uint_as_float(u & 0xFFFF0000u);
}
__device__ __forceinline__ unsigned short f2bf(float f) {
    unsigned int u = __float_as_uint(f);
    u = (u + 0x7FFFu + ((u >> 16) & 1u)) >> 16;   // RNE
    return (unsigned short)u;
}
__device__ __forceinline__ unsigned int pack2(float a, float b) {
    return (unsigned int)f2bf(a) | ((unsigned int)f2bf(b) << 16);
}

// ---------------- CSR build: counting sort of edges by dst --------------
// fused: one launch counts all 3 edge lists
__global__ __launch_bounds__(256) void count_dst3(
    const int* __restrict__ d0, const int* __restrict__ d1, const int* __restrict__ d2,
    int* __restrict__ cnt0, int* __restrict__ cnt1, int* __restrict__ cnt2)
{
    int i = blockIdx.x * blockDim.x + threadIdx.x;
    if (i < E0)                 atomicAdd(&cnt0[d0[i]], 1);
    else if (i < E0 + E1)       atomicAdd(&cnt1[d1[i - E0]], 1);
    else if (i < E0 + E1 + E2)  atomicAdd(&cnt2[d2[i - E0 - E1]], 1);
}

// fused: 3 blocks, one per layer
__global__ __launch_bounds__(1024) void scan_excl3(
    const int* __restrict__ c0, int* __restrict__ u0,
    const int* __restrict__ c1, int* __restrict__ u1,
    const int* __restrict__ c2, int* __restrict__ u2)
{
    __shared__ int part[1024];
    const int* cnt; int* cursor; int n;
    if (blockIdx.x == 0)      { cnt = c0; cursor = u0; n = NN1; }
    else if (blockIdx.x == 1) { cnt = c1; cursor = u1; n = NN2; }
    else                      { cnt = c2; cursor = u2; n = NN3; }
    int t = threadIdx.x;
    int per = (n + 1023) >> 10;
    int lo = t * per;
    int hi = min(n, lo + per);
    int s = 0;
    for (int i = lo; i < hi; ++i) s += cnt[i];
    part[t] = s;
    __syncthreads();
    for (int d = 1; d < 1024; d <<= 1) {
        int v = part[t];
        int add = (t >= d) ? part[t - d] : 0;
        __syncthreads();
        part[t] = v + add;
        __syncthreads();
    }
    int off = (t == 0) ? 0 : part[t - 1];
    for (int i = lo; i < hi; ++i) { cursor[i] = off; off += cnt[i]; }
}

// After fill, cursor[v] == row_end(v); row_start = cursor[v] - cnt[v].
__global__ __launch_bounds__(256) void fill_adj3(
    const int* __restrict__ s0, const int* __restrict__ d0,
    const int* __restrict__ s1, const int* __restrict__ d1,
    const int* __restrict__ s2, const int* __restrict__ d2,
    int* __restrict__ u0, int* __restrict__ u1, int* __restrict__ u2,
    int* __restrict__ a0, int* __restrict__ a1, int* __restrict__ a2)
{
    int i = blockIdx.x * blockDim.x + threadIdx.x;
    if (i < E0) {
        int pos = atomicAdd(&u0[d0[i]], 1);
        a0[pos] = s0[i];
    } else if (i < E0 + E1) {
        int j = i - E0;
        int pos = atomicAdd(&u1[d1[j]], 1);
        a1[pos] = s1[j];
    } else if (i < E0 + E1 + E2) {
        int j = i - E0 - E1;
        int pos = atomicAdd(&u2[d2[j]], 1);
        a2[pos] = s2[j];
    }
}

// ---------------- dtype conversions -------------------------------------
// fp32 -> bf16, 8 elems/thread
__global__ __launch_bounds__(256) void cast_f32_bf16(
    const float* __restrict__ in, unsigned short* __restrict__ out, int n8)
{
    int i = blockIdx.x * blockDim.x + threadIdx.x;
    if (i >= n8) return;
    float4 a = *(const float4*)(in + (size_t)i * 8);
    float4 b = *(const float4*)(in + (size_t)i * 8 + 4);
    uint4 o;
    o.x = pack2(a.x, a.y); o.y = pack2(a.z, a.w);
    o.z = pack2(b.x, b.y); o.w = pack2(b.z, b.w);
    *(uint4*)(out + (size_t)i * 8) = o;
}

// W fp32 [K][N] -> Wt bf16 [N][K]; all 4 weight matrices in one launch.
// tile ranges: [0,256) Wself0, [256,512) Wneigh0, [512,1536) Wself1,
// [1536,2560) Wneigh1
__global__ __launch_bounds__(256) void transpose_cast4(
    const float* __restrict__ Ws0, unsigned short* __restrict__ Ts0,
    const float* __restrict__ Wn0, unsigned short* __restrict__ Tn0,
    const float* __restrict__ Ws1, unsigned short* __restrict__ Ts1,
    const float* __restrict__ Wn1, unsigned short* __restrict__ Tn1)
{
    __shared__ float t[32][33];
    int b = blockIdx.x;
    const float* W; unsigned short* T; int K, tt;
    if (b < 256)       { W = Ws0; T = Ts0; K = F_IN;  tt = b; }
    else if (b < 512)  { W = Wn0; T = Tn0; K = F_IN;  tt = b - 256; }
    else if (b < 1536) { W = Ws1; T = Ts1; K = F_HID; tt = b - 512; }
    else               { W = Wn1; T = Tn1; K = F_HID; tt = b - 1536; }
    const int N = F_HID;          // all weight matrices have N = 1024 cols
    int ktiles = K >> 5;
    int k0 = (tt % ktiles) * 32;
    int n0 = (tt / ktiles) * 32;
    int tx = threadIdx.x & 31;
    int ty = threadIdx.x >> 5;   // 0..7
    #pragma unroll
    for (int i = 0; i < 4; ++i) {
        int r = ty * 4 + i;
        t[r][tx] = W[(size_t)(k0 + r) * N + n0 + tx];
    }
    __syncthreads();
    #pragma unroll
    for (int i = 0; i < 4; ++i) {
        int nr = ty * 4 + i;
        T[(size_t)(n0 + nr) * K + k0 + tx] = f2bf(t[tx][nr]);
    }
}

// ---------------- gather mean (fp32 feat, F=256) -> bf16 ----------------
__global__ __launch_bounds__(256) void gather_mean_f32(
    const float* __restrict__ feat, const int* __restrict__ adj,
    const int* __restrict__ cnt, const int* __restrict__ cur,
    unsigned short* __restrict__ agg, int num_dst)
{
    int wave = (blockIdx.x * blockDim.x + threadIdx.x) >> 6;
    int lane = threadIdx.x & 63;
    if (wave >= num_dst) return;
    int d = cnt[wave];
    int start = cur[wave] - d;
    float4 a0 = make_float4(0.f, 0.f, 0.f, 0.f), a1 = a0, a2 = a0, a3 = a0;
    int j = 0;
    for (; j + 3 < d; j += 4) {
        int i0 = adj[start + j + 0], i1 = adj[start + j + 1];
        int i2 = adj[start + j + 2], i3 = adj[start + j + 3];
        float4 v0 = *(const float4*)(feat + (size_t)i0 * F_IN + lane * 4);
        float4 v1 = *(const float4*)(feat + (size_t)i1 * F_IN + lane * 4);
        float4 v2 = *(const float4*)(feat + (size_t)i2 * F_IN + lane * 4);
        float4 v3 = *(const float4*)(feat + (size_t)i3 * F_IN + lane * 4);
        a0.x += v0.x; a0.y += v0.y; a0.z += v0.z; a0.w += v0.w;
        a1.x += v1.x; a1.y += v1.y; a1.z += v1.z; a1.w += v1.w;
        a2.x += v2.x; a2.y += v2.y; a2.z += v2.z; a2.w += v2.w;
        a3.x += v3.x; a3.y += v3.y; a3.z += v3.z; a3.w += v3.w;
    }
    for (; j < d; ++j) {
        int i0 = adj[start + j];
        float4 v0 = *(const float4*)(feat + (size_t)i0 * F_IN + lane * 4);
        a0.x += v0.x; a0.y += v0.y; a0.z += v0.z; a0.w += v0.w;
    }
    float inv = 1.0f / (float)(d > 0 ? d : 1);
    float sx = (a0.x + a1.x) + (a2.x + a3.x);
    float sy = (a0.y + a1.y) + (a2.y + a3.y);
    float sz = (a0.z + a1.z) + (a2.z + a3.z);
    float sw = (a0.w + a1.w) + (a2.w + a3.w);
    uint2 o;
    o.x = pack2(sx * inv, sy * inv);
    o.y = pack2(sz * inv, sw * inv);
    *(uint2*)(agg + (size_t)wave * F_IN + lane * 4) = o;
}

// ---------------- gather mean (bf16 feat, F=1024) -> bf16 ---------------
__global__ __launch_bounds__(256) void gather_mean_bf16(
    const unsigned short* __restrict__ feat, const int* __restrict__ adj,
    const int* __restrict__ cnt, const int* __restrict__ cur,
    unsigned short* __restrict__ agg, int num_dst)
{
    int wave = (blockIdx.x * blockDim.x + threadIdx.x) >> 6;
    int lane = threadIdx.x & 63;
    if (wave >= num_dst) return;
    int d = cnt[wave];
    int start = cur[wave] - d;
    float acc[16];
    #pragma unroll
    for (int c = 0; c < 16; ++c) acc[c] = 0.f;
    int j = 0;
    for (; j + 1 < d; j += 2) {
        const unsigned short* f0 = feat + (size_t)adj[start + j] * F_HID + lane * 16;
        const unsigned short* f1 = feat + (size_t)adj[start + j + 1] * F_HID + lane * 16;
        uint4 p0 = *(const uint4*)f0;
        uint4 p1 = *(const uint4*)(f0 + 8);
        uint4 q0 = *(const uint4*)f1;
        uint4 q1 = *(const uint4*)(f1 + 8);
        acc[0] += bf_lo(p0.x); acc[1] += bf_hi(p0.x);
        acc[2] += bf_lo(p0.y); acc[3] += bf_hi(p0.y);
        acc[4] += bf_lo(p0.z); acc[5] += bf_hi(p0.z);
        acc[6] += bf_lo(p0.w); acc[7] += bf_hi(p0.w);
        acc[8]  += bf_lo(p1.x); acc[9]  += bf_hi(p1.x);
        acc[10] += bf_lo(p1.y); acc[11] += bf_hi(p1.y);
        acc[12] += bf_lo(p1.z); acc[13] += bf_hi(p1.z);
        acc[14] += bf_lo(p1.w); acc[15] += bf_hi(p1.w);
        acc[0] += bf_lo(q0.x); acc[1] += bf_hi(q0.x);
        acc[2] += bf_lo(q0.y); acc[3] += bf_hi(q0.y);
        acc[4] += bf_lo(q0.z); acc[5] += bf_hi(q0.z);
        acc[6] += bf_lo(q0.w); acc[7] += bf_hi(q0.w);
        acc[8]  += bf_lo(q1.x); acc[9]  += bf_hi(q1.x);
        acc[10] += bf_lo(q1.y); acc[11] += bf_hi(q1.y);
        acc[12] += bf_lo(q1.z); acc[13] += bf_hi(q1.z);
        acc[14] += bf_lo(q1.w); acc[15] += bf_hi(q1.w);
    }
    if (j < d) {
        const unsigned short* f0 = feat + (size_t)adj[start + j] * F_HID + lane * 16;
        uint4 p0 = *(const uint4*)f0;
        uint4 p1 = *(const uint4*)(f0 + 8);
        acc[0] += bf_lo(p0.x); acc[1] += bf_hi(p0.x);
        acc[2] += bf_lo(p0.y); acc[3] += bf_hi(p0.y);
        acc[4] += bf_lo(p0.z); acc[5] += bf_hi(p0.z);
        acc[6] += bf_lo(p0.w); acc[7] += bf_hi(p0.w);
        acc[8]  += bf_lo(p1.x); acc[9]  += bf_hi(p1.x);
        acc[10] += bf_lo(p1.y); acc[11] += bf_hi(p1.y);
        acc[12] += bf_lo(p1.z); acc[13] += bf_hi(p1.z);
        acc[14] += bf_lo(p1.w); acc[15] += bf_hi(p1.w);
    }
    float inv = 1.0f / (float)(d > 0 ? d : 1);
    uint4 o0, o1;
    o0.x = pack2(acc[0] * inv, acc[1] * inv);
    o0.y = pack2(acc[2] * inv, acc[3] * inv);
    o0.z = pack2(acc[4] * inv, acc[5] * inv);
    o0.w = pack2(acc[6] * inv, acc[7] * inv);
    o1.x = pack2(acc[8] * inv, acc[9] * inv);
    o1.y = pack2(acc[10] * inv, acc[11] * inv);
    o1.z = pack2(acc[12] * inv, acc[13] * inv);
    o1.w = pack2(acc[14] * inv, acc[15] * inv);
    unsigned short* ap = agg + (size_t)wave * F_HID + lane * 16;
    *(uint4*)ap = o0;
    *(uint4*)(ap + 8) = o1;
}

// ---------------- bf16 MFMA dual-GEMM: C = A1@W1^T' + A2@W2^T' + b ------
// m97 structure: 128x128 tile, BK=32, linear LDS [128][32] bf16, staging
// via global_load_lds dwordx4 (2 x 16B chunks per thread per tile).
// 4 waves (2x2), each wave 64x64 = 4x4 MFMA tiles of 16x16x32.
// Chunk mapping: linear tile byte offset = chunk*16; row = chunk>>2 (a 32-elem
// bf16 row is 64 B = FOUR 16B chunks), k-elem offset = (chunk&3)*8.
__global__ __launch_bounds__(256, 2) void sage_mfma_gemm(
    const unsigned short* __restrict__ A1, const unsigned short* __restrict__ A2,
    const unsigned short* __restrict__ Wt1, const unsigned short* __restrict__ Wt2,
    const float* __restrict__ bias, unsigned short* __restrict__ C,
    int M, int N, int K, int relu)
{
    __shared__ __align__(16) unsigned short As[128 * 32];
    __shared__ __align__(16) unsigned short Bs[128 * 32];

    const int tid  = threadIdx.x;
    const int wave = tid >> 6;
    const int lane = tid & 63;
    const int wy = wave >> 1, wx = wave & 1;
    const int quad = lane >> 4, l16 = lane & 15;
    const int col0 = blockIdx.x * 128;   // x = col-block (few) -> A reuse in L2/L3
    const int row0 = blockIdx.y * 128;   // y = row-block (many)

    // staging chunk assignment. 128x32 bf16 tile = 8192B = 512 x 16B chunks.
    // round 0: chunk = wave*64 + lane (0..255) -> rows 0..63
    // round 1: chunk = 256 + wave*64 + lane    -> rows 64..127
    const int c0  = wave * 64 + lane;
    const int r0  = c0 >> 2, kq0 = (c0 & 3) * 8;
    const int c1  = c0 + 256;
    const int r1  = c1 >> 2, kq1 = (c1 & 3) * 8;
    unsigned short* ldsA0 = &As[(size_t)wave * 512];         // bytes wave*1024
    unsigned short* ldsA1 = &As[2048 + (size_t)wave * 512];  // bytes 4096+wave*1024
    unsigned short* ldsB0 = &Bs[(size_t)wave * 512];
    unsigned short* ldsB1 = &Bs[2048 + (size_t)wave * 512];

    f32x4 acc[4][4];
    #pragma unroll
    for (int i = 0; i < 4; ++i)
        #pragma unroll
        for (int j = 0; j < 4; ++j)
            acc[i][j] = (f32x4){0.f, 0.f, 0.f, 0.f};

    for (int pass = 0; pass < 2; ++pass) {
        const unsigned short* A  = pass ? A2  : A1;
        const unsigned short* Wt = pass ? Wt2 : Wt1;
        const unsigned short* gA0 = A  + (size_t)(row0 + r0) * K + kq0;
        const unsigned short* gA1 = A  + (size_t)(row0 + r1) * K + kq1;
        const unsigned short* gB0 = Wt + (size_t)(col0 + r0) * K + kq0;
        const unsigned short* gB1 = Wt + (size_t)(col0 + r1) * K + kq1;
        for (int k0 = 0; k0 < K; k0 += 32) {
            gload16(gA0 + k0, ldsA0);
            gload16(gA1 + k0, ldsA1);
            gload16(gB0 + k0, ldsB0);
            gload16(gB1 + k0, ldsB1);
            __syncthreads();   // compiler emits vmcnt(0) drain before barrier
            short8 af[4], bfr[4];
            #pragma unroll
            for (int mi = 0; mi < 4; ++mi)
                af[mi] = *(const short8*)(&As[(wy * 64 + mi * 16 + l16) * 32 + quad * 8]);
            #pragma unroll
            for (int ni = 0; ni < 4; ++ni)
                bfr[ni] = *(const short8*)(&Bs[(wx * 64 + ni * 16 + l16) * 32 + quad * 8]);
            #pragma unroll
            for (int mi = 0; mi < 4; ++mi)
                #pragma unroll
                for (int ni = 0; ni < 4; ++ni)
                    acc[mi][ni] = __builtin_amdgcn_mfma_f32_16x16x32_bf16(
                        af[mi], bfr[ni], acc[mi][ni], 0, 0, 0);
            __syncthreads();   // protect LDS before next-tile overwrite
        }
    }

    // epilogue: C/D layout col=lane&15, row=quad*4+reg
    #pragma unroll
    for (int ni = 0; ni < 4; ++ni) {
        int col = col0 + wx * 64 + ni * 16 + l16;
        float bc = bias[col];
        #pragma unroll
        for (int mi = 0; mi < 4; ++mi) {
            int row = row0 + wy * 64 + mi * 16 + quad * 4;
            #pragma unroll
            for (int r = 0; r < 4; ++r) {
                float v = acc[mi][ni][r] + bc;
                if (relu) v = fmaxf(v, 0.0f);
                C[(size_t)(row + r) * N + col] = f2bf(v);
            }
        }
    }
}

// ---------------- skinny GEMM for the final [512 x 47] layer ------------
// Block per output row; 4 waves split K; LDS reduce; fp32 weights & output.
__global__ __launch_bounds__(256) void skinny_gemm_blk(
    const unsigned short* __restrict__ A1, const unsigned short* __restrict__ A2,
    const float* __restrict__ W1, const float* __restrict__ W2,
    const float* __restrict__ bias, float* __restrict__ C, int K)
{
    __shared__ float red[4][64];
    int m = blockIdx.x;
    int wave = threadIdx.x >> 6;
    int lane = threadIdx.x & 63;
    const unsigned short* a1 = A1 + (size_t)m * K;
    const unsigned short* a2 = A2 + (size_t)m * K;
    float acc = 0.f;
    if (lane < F_OUT) {
        int kb = wave * (K >> 2), ke = kb + (K >> 2);
        #pragma unroll 8
        for (int k = kb; k < ke; ++k) {
            acc = fmaf(bf_lo((unsigned int)a1[k]), W1[(size_t)k * F_OUT + lane], acc);
            acc = fmaf(bf_lo((unsigned int)a2[k]), W2[(size_t)k * F_OUT + lane], acc);
        }
    }
    red[wave][lane] = acc;
    __syncthreads();
    if (wave == 0 && lane < F_OUT) {
        float v = (red[0][lane] + red[1][lane]) + (red[2][lane] + red[3][lane])
                + bias[lane];
        C[(size_t)m * F_OUT + lane] = v;
    }
}

// ---------------- host side ---------------------------------------------
extern "C" void kernel_launch(void* const* d_in, const int* in_sizes, int n_in,
                              void* d_out, int out_size, void* d_ws, size_t ws_size,
                              hipStream_t stream)
{
    const float* x   = (const float*)d_in[0];
    const int* src0  = (const int*)d_in[1];
    const int* dst0  = (const int*)d_in[2];
    const int* src1  = (const int*)d_in[3];
    const int* dst1  = (const int*)d_in[4];
    const int* src2  = (const int*)d_in[5];
    const int* dst2  = (const int*)d_in[6];
    const float* Wself0  = (const float*)d_in[7];
    const float* Wneigh0 = (const float*)d_in[8];
    const float* b0      = (const float*)d_in[9];
    const float* Wself1  = (const float*)d_in[10];
    const float* Wneigh1 = (const float*)d_in[11];
    const float* b1      = (const float*)d_in[12];
    const float* Wself2  = (const float*)d_in[13];
    const float* Wneigh2 = (const float*)d_in[14];
    const float* b2      = (const float*)d_in[15];
    float* out = (float*)d_out;

    // ---- workspace carve-up (bytes, 256B-aligned chunks) ----
    char* base = (char*)d_ws;
    auto alloc = [&](size_t bytes) -> char* {
        char* p = base;
        base += (bytes + 255) & ~(size_t)255;
        return p;
    };
    unsigned short* h0   = (unsigned short*)alloc((size_t)NN1 * F_HID * 2);
    unsigned short* h1   = (unsigned short*)alloc((size_t)NN2 * F_HID * 2);
    unsigned short* agg0 = (unsigned short*)alloc((size_t)NN1 * F_IN * 2);
    unsigned short* agg1 = (unsigned short*)alloc((size_t)NN2 * F_HID * 2);
    unsigned short* agg2 = (unsigned short*)alloc((size_t)NN3 * F_HID * 2);
    unsigned short* xbf  = (unsigned short*)alloc((size_t)NN1 * F_IN * 2);
    unsigned short* Wt0s = (unsigned short*)alloc((size_t)F_HID * F_IN * 2);
    unsigned short* Wt0n = (unsigned short*)alloc((size_t)F_HID * F_IN * 2);
    unsigned short* Wt1s = (unsigned short*)alloc((size_t)F_HID * F_HID * 2);
    unsigned short* Wt1n = (unsigned short*)alloc((size_t)F_HID * F_HID * 2);
    int* cnt0 = (int*)alloc((size_t)(NN1 + NN2 + NN3) * 4);   // contiguous
    int* cnt1 = cnt0 + NN1;
    int* cnt2 = cnt1 + NN2;
    int* cur0 = (int*)alloc((size_t)NN1 * 4);
    int* cur1 = (int*)alloc((size_t)NN2 * 4);
    int* cur2 = (int*)alloc((size_t)NN3 * 4);
    int* adj0 = (int*)alloc((size_t)E0 * 4);
    int* adj1 = (int*)alloc((size_t)E1 * 4);
    int* adj2 = (int*)alloc((size_t)E2 * 4);

    hipMemsetAsync(cnt0, 0, (size_t)(NN1 + NN2 + NN3) * 4, stream);

    // ---- prep: casts / weight transposes (independent of CSR) ----
    int n8 = NN1 * F_IN / 8;
    cast_f32_bf16<<<dim3((n8 + 255) / 256), dim3(256), 0, stream>>>(x, xbf, n8);
    transpose_cast4<<<dim3(2560), dim3(256), 0, stream>>>(
        Wself0, Wt0s, Wneigh0, Wt0n, Wself1, Wt1s, Wneigh1, Wt1n);

    // ---- CSR builds (fused across the 3 layers) ----
    const int ET = E0 + E1 + E2;
    count_dst3<<<dim3((ET + 255) / 256), dim3(256), 0, stream>>>(
        dst0, dst1, dst2, cnt0, cnt1, cnt2);
    scan_excl3<<<dim3(3), dim3(1024), 0, stream>>>(
        cnt0, cur0, cnt1, cur1, cnt2, cur2);
    fill_adj3<<<dim3((ET + 255) / 256), dim3(256), 0, stream>>>(
        src0, dst0, src1, dst1, src2, dst2, cur0, cur1, cur2, adj0, adj1, adj2);

    // ---- Layer 0: gather-mean (fp32 x) + bf16 MFMA dual-GEMM (K=256) ----
    gather_mean_f32<<<dim3(NN1 / 4), dim3(256), 0, stream>>>(
        x, adj0, cnt0, cur0, agg0, NN1);
    sage_mfma_gemm<<<dim3(F_HID / 128, NN1 / 128), dim3(256), 0, stream>>>(
        xbf, agg0, Wt0s, Wt0n, b0, h0, NN1, F_HID, F_IN, 1);

    // ---- Layer 1 (K=1024) ----
    gather_mean_bf16<<<dim3(NN2 / 4), dim3(256), 0, stream>>>(
        h0, adj1, cnt1, cur1, agg1, NN2);
    sage_mfma_gemm<<<dim3(F_HID / 128, NN2 / 128), dim3(256), 0, stream>>>(
        h0, agg1, Wt1s, Wt1n, b1, h1, NN2, F_HID, F_HID, 1);

    // ---- Layer 2: [512, 2x1024] @ [2x1024, 47] -> d_out (fp32) ----
    gather_mean_bf16<<<dim3(NN3 / 4), dim3(256), 0, stream>>>(
        h1, adj2, cnt2, cur2, agg2, NN3);
    skinny_gemm_blk<<<dim3(NN3), dim3(256), 0, stream>>>(
        h1, agg2, Wself2, Wneigh2, b2, out, F_HID);
}

// Round 5
// 954.884 us; speedup vs baseline: 1.0545x; 1.0241x over previous
//
#include <hip/hip_runtime.h>

// ---------------- problem constants (match setup_inputs) ----------------
#define E0 506880
#define E1 30720
#define E2 2560
#define NN0 540672
#define NN1 33792
#define NN2 3072
#define NN3 512
#define F_IN 256
#define F_HID 1024
#define F_OUT 47

// prep_all block-range split (each range divides its work exactly)
#define PREP_CAST_B 4224   // NN1*F_IN/8/256
#define PREP_TR_B   2560   // 256+256+1024+1024 transpose tiles
#define PREP_CNT_B  2110   // (E0+E1+E2)/256
#define PREP_TOTAL_B (PREP_CAST_B + PREP_TR_B + PREP_CNT_B)

typedef __attribute__((ext_vector_type(8))) short short8;  // 8 bf16 = 4 VGPRs
typedef __attribute__((ext_vector_type(4))) float f32x4;   // MFMA C/D frag

// address-space-typed pointers for global_load_lds
typedef __attribute__((address_space(1))) const unsigned int as1_u32;
typedef __attribute__((address_space(3))) unsigned int as3_u32;

// async global->LDS, 16B per lane; LDS dest = wave-uniform base + lane*16
__device__ __forceinline__ void gload16(const unsigned short* g, unsigned short* l) {
    __builtin_amdgcn_global_load_lds((as1_u32*)g, (as3_u32*)l, 16, 0, 0);
}

__device__ __forceinline__ float bf_lo(unsigned int u) {
    return __uint_as_float(u << 16);
}
__device__ __forceinline__ float bf_hi(unsigned int u) {
    return __uint_as_float(u & 0xFFFF0000u);
}
__device__ __forceinline__ unsigned short f2bf(float f) {
    unsigned int u = __float_as_uint(f);
    u = (u + 0x7FFFu + ((u >> 16) & 1u)) >> 16;   // RNE
    return (unsigned short)u;
}
__device__ __forceinline__ unsigned int pack2(float a, float b) {
    return (unsigned int)f2bf(a) | ((unsigned int)f2bf(b) << 16);
}

// ---------------- fused prep: cast + 4 transposes + 3 edge counts -------
// All independent work with inputs ready at t=0; one launch instead of 3.
__global__ __launch_bounds__(256) void prep_all(
    const float* __restrict__ x, unsigned short* __restrict__ xbf,
    const float* __restrict__ Ws0, unsigned short* __restrict__ Ts0,
    const float* __restrict__ Wn0, unsigned short* __restrict__ Tn0,
    const float* __restrict__ Ws1, unsigned short* __restrict__ Ts1,
    const float* __restrict__ Wn1, unsigned short* __restrict__ Tn1,
    const int* __restrict__ d0, const int* __restrict__ d1,
    const int* __restrict__ d2,
    int* __restrict__ cnt0, int* __restrict__ cnt1, int* __restrict__ cnt2)
{
    __shared__ float t[32][33];
    int b = blockIdx.x;
    if (b < PREP_CAST_B) {
        // fp32 -> bf16 cast of x[:NN1], 8 elems/thread (exact coverage)
        int i = b * 256 + threadIdx.x;
        float4 a = *(const float4*)(x + (size_t)i * 8);
        float4 c = *(const float4*)(x + (size_t)i * 8 + 4);
        uint4 o;
        o.x = pack2(a.x, a.y); o.y = pack2(a.z, a.w);
        o.z = pack2(c.x, c.y); o.w = pack2(c.z, c.w);
        *(uint4*)(xbf + (size_t)i * 8) = o;
    } else if (b < PREP_CAST_B + PREP_TR_B) {
        // W fp32 [K][N=1024] -> Wt bf16 [N][K], 32x32 tiles
        int bb = b - PREP_CAST_B;
        const float* W; unsigned short* T; int K, tt;
        if (bb < 256)       { W = Ws0; T = Ts0; K = F_IN;  tt = bb; }
        else if (bb < 512)  { W = Wn0; T = Tn0; K = F_IN;  tt = bb - 256; }
        else if (bb < 1536) { W = Ws1; T = Ts1; K = F_HID; tt = bb - 512; }
        else                { W = Wn1; T = Tn1; K = F_HID; tt = bb - 1536; }
        const int N = F_HID;
        int ktiles = K >> 5;
        int k0 = (tt % ktiles) * 32;
        int n0 = (tt / ktiles) * 32;
        int tx = threadIdx.x & 31;
        int ty = threadIdx.x >> 5;   // 0..7
        #pragma unroll
        for (int i = 0; i < 4; ++i) {
            int r = ty * 4 + i;
            t[r][tx] = W[(size_t)(k0 + r) * N + n0 + tx];
        }
        __syncthreads();
        #pragma unroll
        for (int i = 0; i < 4; ++i) {
            int nr = ty * 4 + i;
            T[(size_t)(n0 + nr) * K + k0 + tx] = f2bf(t[tx][nr]);
        }
    } else {
        // count dst degrees for all 3 edge lists (exact coverage of ET)
        int i = (b - PREP_CAST_B - PREP_TR_B) * 256 + threadIdx.x;
        if (i < E0)           atomicAdd(&cnt0[d0[i]], 1);
        else if (i < E0 + E1) atomicAdd(&cnt1[d1[i - E0]], 1);
        else                  atomicAdd(&cnt2[d2[i - E0 - E1]], 1);
    }
}

// fused: 3 blocks, one per layer
__global__ __launch_bounds__(1024) void scan_excl3(
    const int* __restrict__ c0, int* __restrict__ u0,
    const int* __restrict__ c1, int* __restrict__ u1,
    const int* __restrict__ c2, int* __restrict__ u2)
{
    __shared__ int part[1024];
    const int* cnt; int* cursor; int n;
    if (blockIdx.x == 0)      { cnt = c0; cursor = u0; n = NN1; }
    else if (blockIdx.x == 1) { cnt = c1; cursor = u1; n = NN2; }
    else                      { cnt = c2; cursor = u2; n = NN3; }
    int t = threadIdx.x;
    int per = (n + 1023) >> 10;
    int lo = t * per;
    int hi = min(n, lo + per);
    int s = 0;
    for (int i = lo; i < hi; ++i) s += cnt[i];
    part[t] = s;
    __syncthreads();
    for (int d = 1; d < 1024; d <<= 1) {
        int v = part[t];
        int add = (t >= d) ? part[t - d] : 0;
        __syncthreads();
        part[t] = v + add;
        __syncthreads();
    }
    int off = (t == 0) ? 0 : part[t - 1];
    for (int i = lo; i < hi; ++i) { cursor[i] = off; off += cnt[i]; }
}

// After fill, cursor[v] == row_end(v); row_start = cursor[v] - cnt[v].
__global__ __launch_bounds__(256) void fill_adj3(
    const int* __restrict__ s0, const int* __restrict__ d0,
    const int* __restrict__ s1, const int* __restrict__ d1,
    const int* __restrict__ s2, const int* __restrict__ d2,
    int* __restrict__ u0, int* __restrict__ u1, int* __restrict__ u2,
    int* __restrict__ a0, int* __restrict__ a1, int* __restrict__ a2)
{
    int i = blockIdx.x * blockDim.x + threadIdx.x;
    if (i < E0) {
        int pos = atomicAdd(&u0[d0[i]], 1);
        a0[pos] = s0[i];
    } else if (i < E0 + E1) {
        int j = i - E0;
        int pos = atomicAdd(&u1[d1[j]], 1);
        a1[pos] = s1[j];
    } else if (i < E0 + E1 + E2) {
        int j = i - E0 - E1;
        int pos = atomicAdd(&u2[d2[j]], 1);
        a2[pos] = s2[j];
    }
}

// ---------------- gather mean (fp32 feat, F=256) -> bf16 ----------------
__global__ __launch_bounds__(256) void gather_mean_f32(
    const float* __restrict__ feat, const int* __restrict__ adj,
    const int* __restrict__ cnt, const int* __restrict__ cur,
    unsigned short* __restrict__ agg, int num_dst)
{
    int wave = (blockIdx.x * blockDim.x + threadIdx.x) >> 6;
    int lane = threadIdx.x & 63;
    if (wave >= num_dst) return;
    int d = cnt[wave];
    int start = cur[wave] - d;
    float4 a0 = make_float4(0.f, 0.f, 0.f, 0.f), a1 = a0, a2 = a0, a3 = a0;
    int j = 0;
    for (; j + 3 < d; j += 4) {
        int i0 = adj[start + j + 0], i1 = adj[start + j + 1];
        int i2 = adj[start + j + 2], i3 = adj[start + j + 3];
        float4 v0 = *(const float4*)(feat + (size_t)i0 * F_IN + lane * 4);
        float4 v1 = *(const float4*)(feat + (size_t)i1 * F_IN + lane * 4);
        float4 v2 = *(const float4*)(feat + (size_t)i2 * F_IN + lane * 4);
        float4 v3 = *(const float4*)(feat + (size_t)i3 * F_IN + lane * 4);
        a0.x += v0.x; a0.y += v0.y; a0.z += v0.z; a0.w += v0.w;
        a1.x += v1.x; a1.y += v1.y; a1.z += v1.z; a1.w += v1.w;
        a2.x += v2.x; a2.y += v2.y; a2.z += v2.z; a2.w += v2.w;
        a3.x += v3.x; a3.y += v3.y; a3.z += v3.z; a3.w += v3.w;
    }
    for (; j < d; ++j) {
        int i0 = adj[start + j];
        float4 v0 = *(const float4*)(feat + (size_t)i0 * F_IN + lane * 4);
        a0.x += v0.x; a0.y += v0.y; a0.z += v0.z; a0.w += v0.w;
    }
    float inv = 1.0f / (float)(d > 0 ? d : 1);
    float sx = (a0.x + a1.x) + (a2.x + a3.x);
    float sy = (a0.y + a1.y) + (a2.y + a3.y);
    float sz = (a0.z + a1.z) + (a2.z + a3.z);
    float sw = (a0.w + a1.w) + (a2.w + a3.w);
    uint2 o;
    o.x = pack2(sx * inv, sy * inv);
    o.y = pack2(sz * inv, sw * inv);
    *(uint2*)(agg + (size_t)wave * F_IN + lane * 4) = o;
}

// ---------------- gather mean (bf16 feat, F=1024) -> bf16 ---------------
__global__ __launch_bounds__(256) void gather_mean_bf16(
    const unsigned short* __restrict__ feat, const int* __restrict__ adj,
    const int* __restrict__ cnt, const int* __restrict__ cur,
    unsigned short* __restrict__ agg, int num_dst)
{
    int wave = (blockIdx.x * blockDim.x + threadIdx.x) >> 6;
    int lane = threadIdx.x & 63;
    if (wave >= num_dst) return;
    int d = cnt[wave];
    int start = cur[wave] - d;
    float acc[16];
    #pragma unroll
    for (int c = 0; c < 16; ++c) acc[c] = 0.f;
    int j = 0;
    for (; j + 1 < d; j += 2) {
        const unsigned short* f0 = feat + (size_t)adj[start + j] * F_HID + lane * 16;
        const unsigned short* f1 = feat + (size_t)adj[start + j + 1] * F_HID + lane * 16;
        uint4 p0 = *(const uint4*)f0;
        uint4 p1 = *(const uint4*)(f0 + 8);
        uint4 q0 = *(const uint4*)f1;
        uint4 q1 = *(const uint4*)(f1 + 8);
        acc[0] += bf_lo(p0.x); acc[1] += bf_hi(p0.x);
        acc[2] += bf_lo(p0.y); acc[3] += bf_hi(p0.y);
        acc[4] += bf_lo(p0.z); acc[5] += bf_hi(p0.z);
        acc[6] += bf_lo(p0.w); acc[7] += bf_hi(p0.w);
        acc[8]  += bf_lo(p1.x); acc[9]  += bf_hi(p1.x);
        acc[10] += bf_lo(p1.y); acc[11] += bf_hi(p1.y);
        acc[12] += bf_lo(p1.z); acc[13] += bf_hi(p1.z);
        acc[14] += bf_lo(p1.w); acc[15] += bf_hi(p1.w);
        acc[0] += bf_lo(q0.x); acc[1] += bf_hi(q0.x);
        acc[2] += bf_lo(q0.y); acc[3] += bf_hi(q0.y);
        acc[4] += bf_lo(q0.z); acc[5] += bf_hi(q0.z);
        acc[6] += bf_lo(q0.w); acc[7] += bf_hi(q0.w);
        acc[8]  += bf_lo(q1.x); acc[9]  += bf_hi(q1.x);
        acc[10] += bf_lo(q1.y); acc[11] += bf_hi(q1.y);
        acc[12] += bf_lo(q1.z); acc[13] += bf_hi(q1.z);
        acc[14] += bf_lo(q1.w); acc[15] += bf_hi(q1.w);
    }
    if (j < d) {
        const unsigned short* f0 = feat + (size_t)adj[start + j] * F_HID + lane * 16;
        uint4 p0 = *(const uint4*)f0;
        uint4 p1 = *(const uint4*)(f0 + 8);
        acc[0] += bf_lo(p0.x); acc[1] += bf_hi(p0.x);
        acc[2] += bf_lo(p0.y); acc[3] += bf_hi(p0.y);
        acc[4] += bf_lo(p0.z); acc[5] += bf_hi(p0.z);
        acc[6] += bf_lo(p0.w); acc[7] += bf_hi(p0.w);
        acc[8]  += bf_lo(p1.x); acc[9]  += bf_hi(p1.x);
        acc[10] += bf_lo(p1.y); acc[11] += bf_hi(p1.y);
        acc[12] += bf_lo(p1.z); acc[13] += bf_hi(p1.z);
        acc[14] += bf_lo(p1.w); acc[15] += bf_hi(p1.w);
    }
    float inv = 1.0f / (float)(d > 0 ? d : 1);
    uint4 o0, o1;
    o0.x = pack2(acc[0] * inv, acc[1] * inv);
    o0.y = pack2(acc[2] * inv, acc[3] * inv);
    o0.z = pack2(acc[4] * inv, acc[5] * inv);
    o0.w = pack2(acc[6] * inv, acc[7] * inv);
    o1.x = pack2(acc[8] * inv, acc[9] * inv);
    o1.y = pack2(acc[10] * inv, acc[11] * inv);
    o1.z = pack2(acc[12] * inv, acc[13] * inv);
    o1.w = pack2(acc[14] * inv, acc[15] * inv);
    unsigned short* ap = agg + (size_t)wave * F_HID + lane * 16;
    *(uint4*)ap = o0;
    *(uint4*)(ap + 8) = o1;
}

// ---------------- bf16 MFMA dual-GEMM: C = A1@W1^T' + A2@W2^T' + b ------
// m97 structure: 128x128 tile, BK=32, linear LDS [128][32] bf16, staging
// via global_load_lds dwordx4 (2 x 16B chunks per thread per tile).
// 4 waves (2x2), each wave 64x64 = 4x4 MFMA tiles of 16x16x32.
// Chunk mapping: linear tile byte offset = chunk*16; row = chunk>>2 (a 32-elem
// bf16 row is 64 B = FOUR 16B chunks), k-elem offset = (chunk&3)*8.
// XCD swizzle (T1): nwg%8==0 for both launches (2112, 192); each XCD gets a
// contiguous swz range -> contiguous row-strips; A-panel (33 strips x 128 rows
// x K x 2B ~ 2.2MB at K=256) fits the per-XCD 4MB L2, reused by all col-blocks.
__global__ __launch_bounds__(256, 2) void sage_mfma_gemm(
    const unsigned short* __restrict__ A1, const unsigned short* __restrict__ A2,
    const unsigned short* __restrict__ Wt1, const unsigned short* __restrict__ Wt2,
    const float* __restrict__ bias, unsigned short* __restrict__ C,
    int M, int N, int K, int relu)
{
    __shared__ __align__(16) unsigned short As[128 * 32];
    __shared__ __align__(16) unsigned short Bs[128 * 32];

    const int tid  = threadIdx.x;
    const int wave = tid >> 6;
    const int lane = tid & 63;
    const int wy = wave >> 1, wx = wave & 1;
    const int quad = lane >> 4, l16 = lane & 15;

    // XCD-aware remap of the linear block id (HW round-robins lin%8 -> XCD)
    const int gx  = gridDim.x;
    const int nwg = gx * gridDim.y;
    const int lin = blockIdx.y * gx + blockIdx.x;
    const int cpx = nwg >> 3;
    const int swz = (lin & 7) * cpx + (lin >> 3);
    const int col0 = (swz % gx) * 128;   // x = col-block (few)
    const int row0 = (swz / gx) * 128;   // y = row-block (many)

    // staging chunk assignment. 128x32 bf16 tile = 8192B = 512 x 16B chunks.
    // round 0: chunk = wave*64 + lane (0..255) -> rows 0..63
    // round 1: chunk = 256 + wave*64 + lane    -> rows 64..127
    const int c0  = wave * 64 + lane;
    const int r0  = c0 >> 2, kq0 = (c0 & 3) * 8;
    const int c1  = c0 + 256;
    const int r1  = c1 >> 2, kq1 = (c1 & 3) * 8;
    unsigned short* ldsA0 = &As[(size_t)wave * 512];         // bytes wave*1024
    unsigned short* ldsA1 = &As[2048 + (size_t)wave * 512];  // bytes 4096+wave*1024
    unsigned short* ldsB0 = &Bs[(size_t)wave * 512];
    unsigned short* ldsB1 = &Bs[2048 + (size_t)wave * 512];

    f32x4 acc[4][4];
    #pragma unroll
    for (int i = 0; i < 4; ++i)
        #pragma unroll
        for (int j = 0; j < 4; ++j)
            acc[i][j] = (f32x4){0.f, 0.f, 0.f, 0.f};

    for (int pass = 0; pass < 2; ++pass) {
        const unsigned short* A  = pass ? A2  : A1;
        const unsigned short* Wt = pass ? Wt2 : Wt1;
        const unsigned short* gA0 = A  + (size_t)(row0 + r0) * K + kq0;
        const unsigned short* gA1 = A  + (size_t)(row0 + r1) * K + kq1;
        const unsigned short* gB0 = Wt + (size_t)(col0 + r0) * K + kq0;
        const unsigned short* gB1 = Wt + (size_t)(col0 + r1) * K + kq1;
        for (int k0 = 0; k0 < K; k0 += 32) {
            gload16(gA0 + k0, ldsA0);
            gload16(gA1 + k0, ldsA1);
            gload16(gB0 + k0, ldsB0);
            gload16(gB1 + k0, ldsB1);
            __syncthreads();   // compiler emits vmcnt(0) drain before barrier
            short8 af[4], bfr[4];
            #pragma unroll
            for (int mi = 0; mi < 4; ++mi)
                af[mi] = *(const short8*)(&As[(wy * 64 + mi * 16 + l16) * 32 + quad * 8]);
            #pragma unroll
            for (int ni = 0; ni < 4; ++ni)
                bfr[ni] = *(const short8*)(&Bs[(wx * 64 + ni * 16 + l16) * 32 + quad * 8]);
            #pragma unroll
            for (int mi = 0; mi < 4; ++mi)
                #pragma unroll
                for (int ni = 0; ni < 4; ++ni)
                    acc[mi][ni] = __builtin_amdgcn_mfma_f32_16x16x32_bf16(
                        af[mi], bfr[ni], acc[mi][ni], 0, 0, 0);
            __syncthreads();   // protect LDS before next-tile overwrite
        }
    }

    // epilogue: C/D layout col=lane&15, row=quad*4+reg
    #pragma unroll
    for (int ni = 0; ni < 4; ++ni) {
        int col = col0 + wx * 64 + ni * 16 + l16;
        float bc = bias[col];
        #pragma unroll
        for (int mi = 0; mi < 4; ++mi) {
            int row = row0 + wy * 64 + mi * 16 + quad * 4;
            #pragma unroll
            for (int r = 0; r < 4; ++r) {
                float v = acc[mi][ni][r] + bc;
                if (relu) v = fmaxf(v, 0.0f);
                C[(size_t)(row + r) * N + col] = f2bf(v);
            }
        }
    }
}

// ---------------- fused layer 2: gather-mean + skinny GEMM --------------
// Block per output row m. Phase 1: 4 waves split the neighbor list (avg
// degree 5), accumulate fp32 partials in regs (16 elems/lane), LDS-reduce
// to the fp32 mean a2s[1024] (skips the bf16 agg2 roundtrip). Phase 2:
// 4 waves split K for the [1x2048]@[2048x47] dot, LDS-reduce, write fp32.
__global__ __launch_bounds__(256) void sage_l2_fused(
    const unsigned short* __restrict__ h1, const int* __restrict__ adj,
    const int* __restrict__ cnt, const int* __restrict__ cur,
    const float* __restrict__ W1, const float* __restrict__ W2,
    const float* __restrict__ bias, float* __restrict__ C)
{
    __shared__ float a2p[4][F_HID];   // per-wave gather partials (16 KB)
    __shared__ float a2s[F_HID];      // reduced fp32 mean (4 KB)
    __shared__ float red[4][64];
    int m = blockIdx.x;
    int wave = threadIdx.x >> 6;
    int lane = threadIdx.x & 63;
    int d = cnt[m];
    int start = cur[m] - d;

    float part[16];
    #pragma unroll
    for (int c = 0; c < 16; ++c) part[c] = 0.f;
    for (int j = wave; j < d; j += 4) {
        const unsigned short* f = h1 + (size_t)adj[start + j] * F_HID + lane * 16;
        uint4 p0 = *(const uint4*)f;
        uint4 p1 = *(const uint4*)(f + 8);
        part[0] += bf_lo(p0.x); part[1] += bf_hi(p0.x);
        part[2] += bf_lo(p0.y); part[3] += bf_hi(p0.y);
        part[4] += bf_lo(p0.z); part[5] += bf_hi(p0.z);
        part[6] += bf_lo(p0.w); part[7] += bf_hi(p0.w);
        part[8]  += bf_lo(p1.x); part[9]  += bf_hi(p1.x);
        part[10] += bf_lo(p1.y); part[11] += bf_hi(p1.y);
        part[12] += bf_lo(p1.z); part[13] += bf_hi(p1.z);
        part[14] += bf_lo(p1.w); part[15] += bf_hi(p1.w);
    }
    #pragma unroll
    for (int c = 0; c < 16; ++c) a2p[wave][lane * 16 + c] = part[c];
    __syncthreads();
    float inv = 1.0f / (float)(d > 0 ? d : 1);
    int e0 = threadIdx.x * 4;          // 256 threads x 4 elems = 1024
    #pragma unroll
    for (int c = 0; c < 4; ++c) {
        int e = e0 + c;
        a2s[e] = ((a2p[0][e] + a2p[1][e]) + (a2p[2][e] + a2p[3][e])) * inv;
    }
    __syncthreads();

    const unsigned short* a1 = h1 + (size_t)m * F_HID;
    float acc = 0.f;
    if (lane < F_OUT) {
        int kb = wave * (F_HID / 4), ke = kb + (F_HID / 4);
        #pragma unroll 8
        for (int k = kb; k < ke; ++k) {
            acc = fmaf(bf_lo((unsigned int)a1[k]), W1[(size_t)k * F_OUT + lane], acc);
            acc = fmaf(a2s[k], W2[(size_t)k * F_OUT + lane], acc);
        }
    }
    red[wave][lane] = acc;
    __syncthreads();
    if (wave == 0 && lane < F_OUT) {
        float v = (red[0][lane] + red[1][lane]) + (red[2][lane] + red[3][lane])
                + bias[lane];
        C[(size_t)m * F_OUT + lane] = v;
    }
}

// ---------------- host side ---------------------------------------------
extern "C" void kernel_launch(void* const* d_in, const int* in_sizes, int n_in,
                              void* d_out, int out_size, void* d_ws, size_t ws_size,
                              hipStream_t stream)
{
    const float* x   = (const float*)d_in[0];
    const int* src0  = (const int*)d_in[1];
    const int* dst0  = (const int*)d_in[2];
    const int* src1  = (const int*)d_in[3];
    const int* dst1  = (const int*)d_in[4];
    const int* src2  = (const int*)d_in[5];
    const int* dst2  = (const int*)d_in[6];
    const float* Wself0  = (const float*)d_in[7];
    const float* Wneigh0 = (const float*)d_in[8];
    const float* b0      = (const float*)d_in[9];
    const float* Wself1  = (const float*)d_in[10];
    const float* Wneigh1 = (const float*)d_in[11];
    const float* b1      = (const float*)d_in[12];
    const float* Wself2  = (const float*)d_in[13];
    const float* Wneigh2 = (const float*)d_in[14];
    const float* b2      = (const float*)d_in[15];
    float* out = (float*)d_out;

    // ---- workspace carve-up (bytes, 256B-aligned chunks) ----
    char* base = (char*)d_ws;
    auto alloc = [&](size_t bytes) -> char* {
        char* p = base;
        base += (bytes + 255) & ~(size_t)255;
        return p;
    };
    unsigned short* h0   = (unsigned short*)alloc((size_t)NN1 * F_HID * 2);
    unsigned short* h1   = (unsigned short*)alloc((size_t)NN2 * F_HID * 2);
    unsigned short* agg0 = (unsigned short*)alloc((size_t)NN1 * F_IN * 2);
    unsigned short* agg1 = (unsigned short*)alloc((size_t)NN2 * F_HID * 2);
    unsigned short* xbf  = (unsigned short*)alloc((size_t)NN1 * F_IN * 2);
    unsigned short* Wt0s = (unsigned short*)alloc((size_t)F_HID * F_IN * 2);
    unsigned short* Wt0n = (unsigned short*)alloc((size_t)F_HID * F_IN * 2);
    unsigned short* Wt1s = (unsigned short*)alloc((size_t)F_HID * F_HID * 2);
    unsigned short* Wt1n = (unsigned short*)alloc((size_t)F_HID * F_HID * 2);
    int* cnt0 = (int*)alloc((size_t)(NN1 + NN2 + NN3) * 4);   // contiguous
    int* cnt1 = cnt0 + NN1;
    int* cnt2 = cnt1 + NN2;
    int* cur0 = (int*)alloc((size_t)NN1 * 4);
    int* cur1 = (int*)alloc((size_t)NN2 * 4);
    int* cur2 = (int*)alloc((size_t)NN3 * 4);
    int* adj0 = (int*)alloc((size_t)E0 * 4);
    int* adj1 = (int*)alloc((size_t)E1 * 4);
    int* adj2 = (int*)alloc((size_t)E2 * 4);

    hipMemsetAsync(cnt0, 0, (size_t)(NN1 + NN2 + NN3) * 4, stream);

    // ---- fused prep: cast + 4 weight transposes + 3 edge counts ----
    prep_all<<<dim3(PREP_TOTAL_B), dim3(256), 0, stream>>>(
        x, xbf, Wself0, Wt0s, Wneigh0, Wt0n, Wself1, Wt1s, Wneigh1, Wt1n,
        dst0, dst1, dst2, cnt0, cnt1, cnt2);

    // ---- CSR: scan + fill ----
    const int ET = E0 + E1 + E2;
    scan_excl3<<<dim3(3), dim3(1024), 0, stream>>>(
        cnt0, cur0, cnt1, cur1, cnt2, cur2);
    fill_adj3<<<dim3((ET + 255) / 256), dim3(256), 0, stream>>>(
        src0, dst0, src1, dst1, src2, dst2, cur0, cur1, cur2, adj0, adj1, adj2);

    // ---- Layer 0: gather-mean (fp32 x) + bf16 MFMA dual-GEMM (K=256) ----
    gather_mean_f32<<<dim3(NN1 / 4), dim3(256), 0, stream>>>(
        x, adj0, cnt0, cur0, agg0, NN1);
    sage_mfma_gemm<<<dim3(F_HID / 128, NN1 / 128), dim3(256), 0, stream>>>(
        xbf, agg0, Wt0s, Wt0n, b0, h0, NN1, F_HID, F_IN, 1);

    // ---- Layer 1 (K=1024) ----
    gather_mean_bf16<<<dim3(NN2 / 4), dim3(256), 0, stream>>>(
        h0, adj1, cnt1, cur1, agg1, NN2);
    sage_mfma_gemm<<<dim3(F_HID / 128, NN2 / 128), dim3(256), 0, stream>>>(
        h0, agg1, Wt1s, Wt1n, b1, h1, NN2, F_HID, F_HID, 1);

    // ---- Layer 2: fused gather + [512 x 2048]@[2048 x 47] -> fp32 out ----
    sage_l2_fused<<<dim3(NN3), dim3(256), 0, stream>>>(
        h1, adj2, cnt2, cur2, Wself2, Wneigh2, b2, out);
}